// Round 7
// baseline (77.708 us; speedup 1.0000x reference)
//
#include <hip/hip_runtime.h>
#include <hip/hip_bf16.h>
#include <cstdint>
#include <cstddef>

typedef short short8 __attribute__((ext_vector_type(8)));
typedef float f32x4 __attribute__((ext_vector_type(4)));

constexpr int NR = 8192;   // rows of a  (output rows)
constexpr int MR = 8192;   // rows of b  (output cols)
constexpr int D  = 64;     // feature dim (K)

__device__ inline short f2bf(float f) {
  uint32_t u = __float_as_uint(f);
  u += 0x7fffu + ((u >> 16) & 1u);   // RNE to bf16
  return (short)(u >> 16);
}

// ---------------------------------------------------------------------------
// Single fused kernel — R1's proven GEMM structure (128x128 block tile,
// direct global fragment loads, scalar-store epilogue) with normalization
// folded in-register. Differences vs the failed R3 fusion: NO launch-bounds
// occupancy cap (VGPR-free), NO LDS bounce, NO nontemporal stores.
//
// Fragment layouts (gfx950, HW-verified):
//   A/B in : lane l holds 8 contiguous k-elems: row = l&15, k = (l>>4)*8 ..+7
//   C/D out: col = l&15, row = (l>>4)*4 + reg
// Norm topology: lanes {l, l^16, l^32, l^48} hold the 4 k-slices of one row.
// ---------------------------------------------------------------------------
__global__ __launch_bounds__(256) void cos_fused(
    const float* __restrict__ A, const float* __restrict__ B,
    float* __restrict__ C) {
  int tile = blockIdx.x;
  int tm = tile >> 6;            // 64 tiles along output rows
  int tn = tile & 63;            // 64 tiles along output cols
  int wid  = threadIdx.x >> 6;   // 0..3
  int lane = threadIdx.x & 63;
  int wr = wid >> 1, wc = wid & 1;

  int R0 = tm * 128 + wr * 64;   // output row base for this wave (a rows)
  int C0 = tn * 128 + wc * 64;   // output col base for this wave (b rows)

  int lrow = lane & 15;
  int lk8  = (lane >> 4) * 8;    // this lane's 8-elem k-slice base (0/8/32/40? no:)
  // note: frag k layout is k = (l>>4)*8 within a 32-wide step; for fp32 source
  // we need elements [s*32 + lk8 .. +7] per step s.

  short8 af[4][2], bf[4][2];

  // ---- A fragments: load fp32, in-register row norm, scale, cast bf16 ----
#pragma unroll
  for (int i = 0; i < 4; ++i) {
    const float* p = A + (size_t)(R0 + i * 16 + lrow) * D + lk8;
    float v[16];
    *reinterpret_cast<float4*>(v)      = *reinterpret_cast<const float4*>(p);       // s=0, k lk8..+3
    *reinterpret_cast<float4*>(v + 4)  = *reinterpret_cast<const float4*>(p + 4);   // s=0, +4..7
    *reinterpret_cast<float4*>(v + 8)  = *reinterpret_cast<const float4*>(p + 32);  // s=1
    *reinterpret_cast<float4*>(v + 12) = *reinterpret_cast<const float4*>(p + 36);
    float ss = 0.f;
#pragma unroll
    for (int e = 0; e < 16; ++e) ss += v[e] * v[e];
    ss += __shfl_xor(ss, 16);
    ss += __shfl_xor(ss, 32);
    float sc = rsqrtf(ss);
    short t[16];
#pragma unroll
    for (int e = 0; e < 16; ++e) t[e] = f2bf(v[e] * sc);
    af[i][0] = *reinterpret_cast<short8*>(t);
    af[i][1] = *reinterpret_cast<short8*>(t + 8);
  }

  // ---- B fragments: same over b rows ----
#pragma unroll
  for (int j = 0; j < 4; ++j) {
    const float* p = B + (size_t)(C0 + j * 16 + lrow) * D + lk8;
    float v[16];
    *reinterpret_cast<float4*>(v)      = *reinterpret_cast<const float4*>(p);
    *reinterpret_cast<float4*>(v + 4)  = *reinterpret_cast<const float4*>(p + 4);
    *reinterpret_cast<float4*>(v + 8)  = *reinterpret_cast<const float4*>(p + 32);
    *reinterpret_cast<float4*>(v + 12) = *reinterpret_cast<const float4*>(p + 36);
    float ss = 0.f;
#pragma unroll
    for (int e = 0; e < 16; ++e) ss += v[e] * v[e];
    ss += __shfl_xor(ss, 16);
    ss += __shfl_xor(ss, 32);
    float sc = rsqrtf(ss);
    short t[16];
#pragma unroll
    for (int e = 0; e < 16; ++e) t[e] = f2bf(v[e] * sc);
    bf[j][0] = *reinterpret_cast<short8*>(t);
    bf[j][1] = *reinterpret_cast<short8*>(t + 8);
  }

  // ---- MFMA: K=64 as two 32-wide steps ----
  f32x4 acc[4][4] = {};
#pragma unroll
  for (int s = 0; s < 2; ++s)
#pragma unroll
    for (int i = 0; i < 4; ++i)
#pragma unroll
      for (int j = 0; j < 4; ++j)
        acc[i][j] = __builtin_amdgcn_mfma_f32_16x16x32_bf16(
            af[i][s], bf[j][s], acc[i][j], 0, 0, 0);

  // ---- epilogue: R1's proven scalar stores ----
  int crow = (lane >> 4) * 4;
  int ccol = lane & 15;
#pragma unroll
  for (int i = 0; i < 4; ++i) {
#pragma unroll
    for (int j = 0; j < 4; ++j) {
      float* p = C + (size_t)(R0 + i * 16 + crow) * MR + (C0 + j * 16 + ccol);
#pragma unroll
      for (int r = 0; r < 4; ++r)
        p[(size_t)r * MR] = acc[i][j][r];
    }
  }
}

// ---------------------------------------------------------------------------
extern "C" void kernel_launch(void* const* d_in, const int* in_sizes, int n_in,
                              void* d_out, int out_size, void* d_ws, size_t ws_size,
                              hipStream_t stream) {
  const float* a = (const float*)d_in[0];
  const float* b = (const float*)d_in[1];
  float* out = (float*)d_out;

  // (8192/128)^2 = 4096 tiles
  cos_fused<<<4096, 256, 0, stream>>>(a, b, out);
}